// Round 4
// baseline (410.869 us; speedup 1.0000x reference)
//
#include <hip/hip_runtime.h>
#include <hip/hip_bf16.h>

// GQA bf16-MFMA pipeline. B=2, S=2048, H=2048, 32 heads = 8 groups x 4, d=64.
// prep_k:   x -> xb (bf16); W* -> W*T (N x K bf16, contiguous qkv+o); mask flags
// mm_qkv/mm_out: 128x256-tile 8-phase GEMM (512 thr, 8 waves 2Mx4N = 64x64/wave,
//           BK=64, LDS 96KB: A 4x8KB + B 4x16KB regions, counted vmcnt(6) +
//           raw s_barrier, chunk-XOR swizzle, setprio around MFMA clusters).
//           Grids 384/256 blocks -> full 256-CU subscription (round-3's 256^2
//           tiles gave 192/128 blocks = idle CUs; geometry fixed, schedule kept).
// attn_k:   flash S^T/O^T, 1 head/block, double-buffered K/V (2-phase),
//           no-max exp2 softmax, row-sum l via all-ones MFMA.
// attnb reuses xb (dead after projections). WqT..WvT contiguous = 3072x2048.

#define DEVINL __device__ __forceinline__

typedef __attribute__((ext_vector_type(8))) short bf16x8;
typedef __attribute__((ext_vector_type(4))) float f32x4;

DEVINL unsigned short f2bf(float f) {
  unsigned u = __builtin_bit_cast(unsigned, f);
  u += 0x7fffu + ((u >> 16) & 1u);          // RNE
  return (unsigned short)(u >> 16);
}

DEVINL unsigned pk2bf(float a, float b) {   // HW v_cvt_pk_bf16_f32 (RNE)
  __hip_bfloat162 h = __float22bfloat162_rn(float2{a, b});
  unsigned r;
  __builtin_memcpy(&r, &h, 4);
  return r;
}

DEVINL void gl_lds16(const void* g, void* l) {
  __builtin_amdgcn_global_load_lds(
      (const __attribute__((address_space(1))) void*)g,
      (__attribute__((address_space(3))) void*)l, 16, 0, 0);
}

// ------------- prep: cast x, transpose-cast weights, mask tile flags -------------
__global__ __launch_bounds__(256)
void prep_k(const float* __restrict__ x,
            const float* __restrict__ Wq, const float* __restrict__ Wk,
            const float* __restrict__ Wv, const float* __restrict__ Wo,
            const int* __restrict__ mask,
            unsigned short* __restrict__ xb,
            unsigned short* __restrict__ WqT, unsigned short* __restrict__ WkT,
            unsigned short* __restrict__ WvT, unsigned short* __restrict__ WoT,
            int* __restrict__ flags)
{
  __shared__ float tile[64][68];
  __shared__ int fl[4];
  int blk = blockIdx.x;
  const int tid = threadIdx.x;
  if (blk < 4096) {                      // x cast
    size_t base = (size_t)blk * 2048 + tid * 8;
    float4 f0 = *(const float4*)&x[base];
    float4 f1 = *(const float4*)&x[base + 4];
    uint4 o;
    o.x = pk2bf(f0.x, f0.y); o.y = pk2bf(f0.z, f0.w);
    o.z = pk2bf(f1.x, f1.y); o.w = pk2bf(f1.z, f1.w);
    *(uint4*)&xb[base] = o;
    return;
  }
  blk -= 4096;
  if (blk >= 2560) {                     // mask tile flags: 512 blocks, 128x64 tiles
    int fb = blk - 2560;
    int qt = fb >> 5, tt = fb & 31;
    bool hz = false;
#pragma unroll
    for (int it = 0; it < 8; ++it) {
      int l = it * 1024 + tid * 4;
      int row = l >> 6, col = l & 63;
      int4 mv = *(const int4*)&mask[(size_t)(qt * 128 + row) * 2048 + tt * 64 + col];
      hz |= (mv.x == 0) | (mv.y == 0) | (mv.z == 0) | (mv.w == 0);
    }
    unsigned long long bal = __ballot(hz);
    if ((tid & 63) == 0) fl[tid >> 6] = (bal != 0ull) ? 1 : 0;
    __syncthreads();
    if (tid == 0) flags[fb] = fl[0] | fl[1] | fl[2] | fl[3];
    return;
  }
  const float* W; unsigned short* WT; int N;
  if (blk < 1024)      { W = Wq; WT = WqT; N = 2048; }
  else if (blk < 1280) { W = Wk; WT = WkT; N = 512;  blk -= 1024; }
  else if (blk < 1536) { W = Wv; WT = WvT; N = 512;  blk -= 1280; }
  else                 { W = Wo; WT = WoT; N = 2048; blk -= 1536; }
  const int kt = blk & 31, nt = blk >> 5;
  const int k0 = kt * 64, n0 = nt * 64;
  const int tr = tid >> 4, tc4 = (tid & 15) * 4;
#pragma unroll
  for (int it = 0; it < 4; ++it) {
    int k = it * 16 + tr;
    float4 v = *(const float4*)&W[(size_t)(k0 + k) * N + n0 + tc4];
    tile[tc4 + 0][k] = v.x; tile[tc4 + 1][k] = v.y;
    tile[tc4 + 2][k] = v.z; tile[tc4 + 3][k] = v.w;
  }
  __syncthreads();
#pragma unroll
  for (int it = 0; it < 4; ++it) {
    int n = it * 16 + tr;
    uint2 o;
    o.x = pk2bf(tile[n][tc4 + 0], tile[n][tc4 + 1]);
    o.y = pk2bf(tile[n][tc4 + 2], tile[n][tc4 + 3]);
    *(uint2*)&WT[(size_t)(n0 + n) * 2048 + k0 + tc4] = o;
  }
}

// ================ 128x256 8-phase GEMM core (K=2048, BK=64) ================
// LDS regions (per buf(2) x khalf(2)): A [128 rows][32 k] = 8KB, B [256][32]
// = 16KB. Swizzle: 8-elem chunk c stored at c ^ ((row>>1)&3); gl_lds dest
// linear, global SOURCE pre-swizzled (both-sides rule). Schedule per K-tile t:
//   HG0: STAGE(t+1,kh1); read kh0 frags; 16 MFMA; vmcnt(6); s_barrier
//   HG1: STAGE(t+2,kh0); read kh1 frags; 16 MFMA; vmcnt(6); s_barrier
// STAGE = 3 gl_lds per thread (1 A, 2 B); vmcnt(6) = 2 STAGEs in flight ->
// never drains. Region-liveness race-free: each STAGE targets the region last
// read two barriers ago (verified structure from round 3, which passed).
// Epilogue stages clamp to t=31 (re-stage of identical data, benign).

#define GEMM_WAITB() do { \
    asm volatile("s_waitcnt vmcnt(6)" ::: "memory"); \
    __builtin_amdgcn_s_barrier(); \
  } while (0)

#define GEMM_STAGE(t, kh) do { \
    const int _rg = (((t) & 1) * 2 + (kh)); \
    const size_t _ko = (size_t)(t) * 64 + (kh) * 32; \
    gl_lds16(Asrc0 + _ko, As + _rg * 4096 + tid * 8); \
    gl_lds16(Bsrc0 + _ko, Bs + _rg * 8192 + tid * 8); \
    gl_lds16(Bsrc1 + _ko, Bs + _rg * 8192 + 4096 + tid * 8); \
  } while (0)

#define GEMM_HALFGROUP(t, kh) do { \
    const unsigned short* _ab = As + (((t) & 1) * 2 + (kh)) * 4096; \
    const unsigned short* _bb = Bs + (((t) & 1) * 2 + (kh)) * 8192; \
    bf16x8 bfr[4], af[4]; \
    _Pragma("unroll") \
    for (int nt = 0; nt < 4; ++nt) { \
      const int brow = wn * 64 + nt * 16 + l15; \
      bfr[nt] = *(const bf16x8*)&_bb[brow * 32 + ((quad ^ ((brow >> 1) & 3)) * 8)]; \
    } \
    _Pragma("unroll") \
    for (int mt = 0; mt < 4; ++mt) { \
      const int arow = wm * 64 + mt * 16 + l15; \
      af[mt] = *(const bf16x8*)&_ab[arow * 32 + ((quad ^ ((arow >> 1) & 3)) * 8)]; \
    } \
    __builtin_amdgcn_s_setprio(1); \
    _Pragma("unroll") \
    for (int mt = 0; mt < 4; ++mt) \
      _Pragma("unroll") \
      for (int nt = 0; nt < 4; ++nt) \
        acc[mt][nt] = __builtin_amdgcn_mfma_f32_16x16x32_bf16( \
            af[mt], bfr[nt], acc[mt][nt], 0, 0, 0); \
    __builtin_amdgcn_s_setprio(0); \
  } while (0)

#define GEMM_KLOOP_BODY(Aptr, Bptr) \
  const int tid = threadIdx.x; \
  const int lane = tid & 63, l15 = lane & 15, quad = lane >> 4; \
  const int w = tid >> 6, wm = w & 1, wn = w >> 1; \
  const int row0 = blockIdx.y * 128; \
  const int col0 = blockIdx.x * 256; \
  f32x4 acc[4][4]; \
  _Pragma("unroll") \
  for (int mt = 0; mt < 4; ++mt) \
    _Pragma("unroll") \
    for (int nt = 0; nt < 4; ++nt) acc[mt][nt] = (f32x4){0.f, 0.f, 0.f, 0.f}; \
  const int sr = tid >> 2; \
  const int sc = ((tid & 3) ^ ((sr >> 1) & 3)) * 8; \
  const unsigned short* Asrc0 = (Aptr) + (size_t)(row0 + sr) * 2048 + sc; \
  const unsigned short* Bsrc0 = (Bptr) + (size_t)(col0 + sr) * 2048 + sc; \
  const unsigned short* Bsrc1 = (Bptr) + (size_t)(col0 + sr + 128) * 2048 + sc; \
  GEMM_STAGE(0, 0); \
  GEMM_STAGE(0, 1); \
  GEMM_STAGE(1, 0); \
  GEMM_WAITB(); \
  for (int t = 0; t < 32; ++t) { \
    const int tn1 = (t + 1 < 32) ? t + 1 : 31; \
    const int tn2 = (t + 2 < 32) ? t + 2 : 31; \
    GEMM_STAGE(tn1, 1); \
    GEMM_HALFGROUP(t, 0); \
    GEMM_WAITB(); \
    GEMM_STAGE(tn2, 0); \
    GEMM_HALFGROUP(t, 1); \
    GEMM_WAITB(); \
  }

// ---------------- fused QKV GEMM: A(4096x2048) x Wqkv^T(3072x2048) ----------------
__global__ __launch_bounds__(512, 2)
void mm_qkv(const unsigned short* __restrict__ A,
            const unsigned short* __restrict__ Wt,   // 3072 x 2048 (q|k|v rows)
            const float* __restrict__ bq, const float* __restrict__ bk,
            const float* __restrict__ bv,
            unsigned short* __restrict__ qb, unsigned short* __restrict__ kb,
            unsigned short* __restrict__ vb)
{
  __shared__ __align__(16) unsigned short As[16384];   // 32KB: 4 x 8KB regions
  __shared__ __align__(16) unsigned short Bs[32768];   // 64KB: 4 x 16KB regions
  GEMM_KLOOP_BODY(A, Wt)

  const int rb = row0 + wm * 64 + quad * 4;
#pragma unroll
  for (int nt = 0; nt < 4; ++nt) {
    const int cg = col0 + wn * 64 + nt * 16 + l15;
#pragma unroll
    for (int mt = 0; mt < 4; ++mt) {
#pragma unroll
      for (int reg = 0; reg < 4; ++reg) {
        const int r = rb + mt * 16 + reg;
        const int bb = r >> 11, ss = r & 2047;
        float v = acc[mt][nt][reg];
        if (col0 < 2048) {               // q (block-uniform; 256-tiles don't straddle)
          v += bq[cg];
          int g = cg >> 8, p = (cg >> 6) & 3, d = cg & 63;
          qb[(((size_t)((bb * 8 + g) * 4 + p)) * 2048 + ss) * 64 + d] =
              f2bf(v * 0.1803368801111244f);   // 0.125 * log2(e)
        } else if (col0 < 2560) {        // k
          int cl = cg - 2048;
          v += bk[cl];
          int g = cl >> 6, d = cl & 63;
          kb[((size_t)(bb * 8 + g) * 2048 + ss) * 64 + d] = f2bf(v);
        } else {                         // v (transposed)
          int cl = cg - 2560;
          v += bv[cl];
          int g = cl >> 6, d = cl & 63;
          vb[((size_t)(bb * 8 + g) * 64 + d) * 2048 + ss] = f2bf(v);
        }
      }
    }
  }
}

// ---------------- output-projection GEMM (128x256 8-phase, fp32 out) ----------------
__global__ __launch_bounds__(512, 2)
void mm_out(const unsigned short* __restrict__ A,
            const unsigned short* __restrict__ Bt,
            const float* __restrict__ bias, float* __restrict__ Of)
{
  __shared__ __align__(16) unsigned short As[16384];
  __shared__ __align__(16) unsigned short Bs[32768];
  GEMM_KLOOP_BODY(A, Bt)

  const int rb = row0 + wm * 64 + quad * 4;
#pragma unroll
  for (int nt = 0; nt < 4; ++nt) {
    const int cg = col0 + wn * 64 + nt * 16 + l15;
    const float bvv = bias[cg];
#pragma unroll
    for (int mt = 0; mt < 4; ++mt)
#pragma unroll
      for (int reg = 0; reg < 4; ++reg) {
        const int r = rb + mt * 16 + reg;
        Of[(size_t)r * 2048 + cg] = acc[mt][nt][reg] + bvv;
      }
  }
}

// -------- flash attention: 1 head/block, double-buffered K/V, exp2 softmax --------
// (unchanged from round 2)
__global__ __launch_bounds__(256, 3)
void attn_k(const unsigned short* __restrict__ qb,
            const unsigned short* __restrict__ kb,
            const unsigned short* __restrict__ vb,
            const int* __restrict__ mask, const int* __restrict__ flags,
            unsigned short* __restrict__ attnb)
{
  __shared__ __align__(16) unsigned short Ks[2][64 * 64];  // [buf][t][d], swizzled
  __shared__ __align__(16) unsigned short Vs[2][64 * 64];  // [buf][d][t], swizzled
  __shared__ __align__(16) unsigned short Ps[128 * 72];    // [s_loc][t], wave-private
  const int tid = threadIdx.x;
  const int lane = tid & 63, w = tid >> 6;
  const int l15 = lane & 15, quad = lane >> 4;
  const int q0 = blockIdx.x * 128;
  const int pr = blockIdx.y;            // b(2) x g(8) x p(4)
  const int b = pr >> 5, g = (pr >> 2) & 7, p = pr & 3;
  const int bg = b * 8 + g;

  const unsigned short* Kg = kb + (size_t)bg * 2048 * 64;
  const unsigned short* Vg = vb + (size_t)bg * 64 * 2048;
  const unsigned short* Qg = qb + (size_t)(bg * 4 + p) * 2048 * 64;

  // Q fragments (resident)
  bf16x8 qf[2][2];                      // [u][half]
#pragma unroll
  for (int u = 0; u < 2; ++u) {
    const size_t qrow = (size_t)(q0 + w * 32 + u * 16 + l15) * 64;
    qf[u][0] = *(const bf16x8*)&Qg[qrow + quad * 8];
    qf[u][1] = *(const bf16x8*)&Qg[qrow + 32 + quad * 8];
  }

  bf16x8 ones;
#pragma unroll
  for (int i = 0; i < 8; ++i) ones[i] = (short)0x3F80;   // bf16 1.0

  f32x4 acc_o[4][2];                    // [dt][u]
  f32x4 acc_l[2];                       // [u] row-sum accumulator
#pragma unroll
  for (int u = 0; u < 2; ++u) acc_l[u] = (f32x4){0.f, 0.f, 0.f, 0.f};
#pragma unroll
  for (int dt = 0; dt < 4; ++dt)
#pragma unroll
    for (int u = 0; u < 2; ++u) acc_o[dt][u] = (f32x4){0.f, 0.f, 0.f, 0.f};

  const int c0 = tid, c1 = 256 + tid;
  const int kr0 = c0 >> 3, kx0 = ((c0 & 7) ^ (kr0 & 7)) * 8;
  const int kr1 = c1 >> 3, kx1 = ((c1 & 7) ^ (kr1 & 7)) * 8;

  // prologue: stage tile 0 into buf 0
  gl_lds16(Kg + (size_t)kr0 * 64 + kx0, &Ks[0][(size_t)c0 * 8]);
  gl_lds16(Kg + (size_t)kr1 * 64 + kx1, &Ks[0][(size_t)c1 * 8]);
  gl_lds16(Vg + (size_t)kr0 * 2048 + kx0, &Vs[0][(size_t)c0 * 8]);
  gl_lds16(Vg + (size_t)kr1 * 2048 + kx1, &Vs[0][(size_t)c1 * 8]);
  __syncthreads();                       // vmcnt(0) drain: tile 0 resident

  for (int it = 0; it < 32; ++it) {
    const int cur = it & 1;
    const int t0 = it << 6;
    if (it < 31) {                       // issue next tile's staging FIRST
      const int tn = t0 + 64;
      gl_lds16(Kg + (size_t)(tn + kr0) * 64 + kx0, &Ks[cur ^ 1][(size_t)c0 * 8]);
      gl_lds16(Kg + (size_t)(tn + kr1) * 64 + kx1, &Ks[cur ^ 1][(size_t)c1 * 8]);
      gl_lds16(Vg + (size_t)kr0 * 2048 + tn + kx0, &Vs[cur ^ 1][(size_t)c0 * 8]);
      gl_lds16(Vg + (size_t)kr1 * 2048 + tn + kx1, &Vs[cur ^ 1][(size_t)c1 * 8]);
    }
    const unsigned short* Kc = Ks[cur];
    const unsigned short* Vc = Vs[cur];

    // K fragments
    bf16x8 kf[4][2];
#pragma unroll
    for (int nt = 0; nt < 4; ++nt) {
      const int trow = nt * 16 + l15, ks = trow & 7;
      kf[nt][0] = *(const bf16x8*)&Kc[trow * 64 + ((quad ^ ks) * 8)];
      kf[nt][1] = *(const bf16x8*)&Kc[trow * 64 + (((4 + quad) ^ ks) * 8)];
    }
    const bool msk = flags[blockIdx.x * 32 + it] != 0;

    // S^T = K Q^T -> exp2 -> P^T into Ps (per u-subtile)
#pragma unroll
    for (int u = 0; u < 2; ++u) {
      f32x4 st[4];
#pragma unroll
      for (int nt = 0; nt < 4; ++nt) {
        f32x4 z = (f32x4){0.f, 0.f, 0.f, 0.f};
        z = __builtin_amdgcn_mfma_f32_16x16x32_bf16(kf[nt][0], qf[u][0], z, 0, 0, 0);
        st[nt] = __builtin_amdgcn_mfma_f32_16x16x32_bf16(kf[nt][1], qf[u][1], z, 0, 0, 0);
      }
      if (msk) {
        const size_t mrow = (size_t)(q0 + w * 32 + u * 16 + l15) * 2048;
#pragma unroll
        for (int nt = 0; nt < 4; ++nt) {
          int4 mv = *(const int4*)&mask[mrow + t0 + nt * 16 + quad * 4];
          if (mv.x == 0) st[nt][0] = -1e30f;
          if (mv.y == 0) st[nt][1] = -1e30f;
          if (mv.z == 0) st[nt][2] = -1e30f;
          if (mv.w == 0) st[nt][3] = -1e30f;
        }
      }
      const int srow = w * 32 + u * 16 + l15;
#pragma unroll
      for (int nt = 0; nt < 4; ++nt) {
        float p0 = __builtin_amdgcn_exp2f(st[nt][0]);
        float p1 = __builtin_amdgcn_exp2f(st[nt][1]);
        float p2 = __builtin_amdgcn_exp2f(st[nt][2]);
        float p3 = __builtin_amdgcn_exp2f(st[nt][3]);
        uint2 pkd;
        pkd.x = pk2bf(p0, p1);
        pkd.y = pk2bf(p2, p3);
        *(uint2*)&Ps[srow * 72 + nt * 16 + quad * 4] = pkd;
      }
    }
    asm volatile("s_waitcnt lgkmcnt(0)" ::: "memory");  // Ps rows wave-private

    bf16x8 pf[2][2];
#pragma unroll
    for (int u = 0; u < 2; ++u) {
      const int srow = w * 32 + u * 16 + l15;
      pf[u][0] = *(const bf16x8*)&Ps[srow * 72 + quad * 8];
      pf[u][1] = *(const bf16x8*)&Ps[srow * 72 + 32 + quad * 8];
      // l += 1-vector . P^T  (every lane gets the full 32-key sum)
      acc_l[u] = __builtin_amdgcn_mfma_f32_16x16x32_bf16(ones, pf[u][0], acc_l[u], 0, 0, 0);
      acc_l[u] = __builtin_amdgcn_mfma_f32_16x16x32_bf16(ones, pf[u][1], acc_l[u], 0, 0, 0);
    }
    // O^T += V^T P^T
#pragma unroll
    for (int dt = 0; dt < 4; ++dt) {
      const int drow = dt * 16 + l15, ks = drow & 7;
      bf16x8 v0 = *(const bf16x8*)&Vc[drow * 64 + ((quad ^ ks) * 8)];
      bf16x8 v1 = *(const bf16x8*)&Vc[drow * 64 + (((4 + quad) ^ ks) * 8)];
#pragma unroll
      for (int u = 0; u < 2; ++u) {
        acc_o[dt][u] = __builtin_amdgcn_mfma_f32_16x16x32_bf16(v0, pf[u][0], acc_o[dt][u], 0, 0, 0);
        acc_o[dt][u] = __builtin_amdgcn_mfma_f32_16x16x32_bf16(v1, pf[u][1], acc_o[dt][u], 0, 0, 0);
      }
    }
    __syncthreads();   // reads(t) done; next-tile staging (vmcnt) drained here
  }

  // epilogue: O^T / l  (l identical across quads and regs -> no reduction)
  const int hh = g * 4 + p;
#pragma unroll
  for (int u = 0; u < 2; ++u) {
    const float inv = 1.0f / acc_l[u][0];
    const int s = q0 + w * 32 + u * 16 + l15;
#pragma unroll
    for (int dt = 0; dt < 4; ++dt) {
      uint2 o;
      o.x = pk2bf(acc_o[dt][u][0] * inv, acc_o[dt][u][1] * inv);
      o.y = pk2bf(acc_o[dt][u][2] * inv, acc_o[dt][u][3] * inv);
      *(uint2*)&attnb[((size_t)(b * 2048 + s)) * 2048 + hh * 64 + dt * 16 + quad * 4] = o;
    }
  }
}

extern "C" void kernel_launch(void* const* d_in, const int* in_sizes, int n_in,
                              void* d_out, int out_size, void* d_ws, size_t ws_size,
                              hipStream_t stream)
{
  (void)in_sizes; (void)n_in; (void)out_size; (void)ws_size;
  const float* x  = (const float*)d_in[0];
  const int* mask = (const int*)d_in[1];
  const float* Wq = (const float*)d_in[2];
  const float* bq = (const float*)d_in[3];
  const float* Wk = (const float*)d_in[4];
  const float* bk = (const float*)d_in[5];
  const float* Wv = (const float*)d_in[6];
  const float* bv = (const float*)d_in[7];
  const float* Wo = (const float*)d_in[8];
  const float* bo = (const float*)d_in[9];
  float* out = (float*)d_out;

  unsigned short* xb  = (unsigned short*)d_ws;       // 8388608
  unsigned short* WqT = xb  + 8388608;               // 4194304 (qkv contiguous)
  unsigned short* WkT = WqT + 4194304;               // 1048576 (qkv contiguous)
  unsigned short* WvT = WkT + 1048576;               // 1048576 (qkv contiguous)
  unsigned short* WoT = WvT + 1048576;               // 4194304
  unsigned short* qb  = WoT + 4194304;               // 8388608
  unsigned short* kb  = qb  + 8388608;               // 2097152
  unsigned short* vb  = kb  + 2097152;               // 2097152
  int* flags = (int*)(vb + 2097152);                 // 512 ints
  unsigned short* attnb = xb;                        // reuse

  hipLaunchKernelGGL(prep_k, dim3(7168), dim3(256), 0, stream,
                     x, Wq, Wk, Wv, Wo, mask, xb, WqT, WkT, WvT, WoT, flags);
  hipLaunchKernelGGL(mm_qkv, dim3(12, 32), dim3(512), 0, stream,
                     xb, WqT, bq, bk, bv, qb, kb, vb);
  hipLaunchKernelGGL(attn_k, dim3(16, 64), dim3(256), 0, stream,
                     qb, kb, vb, mask, flags, attnb);
  hipLaunchKernelGGL(mm_out, dim3(8, 32), dim3(512), 0, stream,
                     attnb, WoT, bo, out);
}

// Round 5
// 349.231 us; speedup vs baseline: 1.1765x; 1.1765x over previous
//
#include <hip/hip_runtime.h>
#include <hip/hip_bf16.h>

// GQA bf16-MFMA pipeline. B=2, S=2048, H=2048, 32 heads = 8 groups x 4, d=64.
// prep_k:   x -> xb (bf16); W* -> W*T (N x K bf16, contiguous qkv+o); mask flags
// mm_qkv:   one GEMM over N=3072 (m97 128^2 structure, reverted from failed
//           8-phase ports of rounds 3-4): qb(scaled,scatter) | kb | vb(transposed)
// attn_k:   flash S^T/O^T, 512 thr / 8 waves, q-tile 256, 1 head/block,
//           double-buffered K/V (2-phase), XCD-swizzled block order,
//           no-max exp2 softmax, row-sum l via all-ones MFMA.
// mm_out:   out = attnb Wo + bo (fp32), m97 structure.
// attnb reuses xb (dead after projections). WqT..WvT contiguous = 3072x2048.

#define DEVINL __device__ __forceinline__

typedef __attribute__((ext_vector_type(8))) short bf16x8;
typedef __attribute__((ext_vector_type(4))) float f32x4;

DEVINL unsigned short f2bf(float f) {
  unsigned u = __builtin_bit_cast(unsigned, f);
  u += 0x7fffu + ((u >> 16) & 1u);          // RNE
  return (unsigned short)(u >> 16);
}

DEVINL unsigned pk2bf(float a, float b) {   // HW v_cvt_pk_bf16_f32 (RNE)
  __hip_bfloat162 h = __float22bfloat162_rn(float2{a, b});
  unsigned r;
  __builtin_memcpy(&r, &h, 4);
  return r;
}

DEVINL void gl_lds16(const void* g, void* l) {
  __builtin_amdgcn_global_load_lds(
      (const __attribute__((address_space(1))) void*)g,
      (__attribute__((address_space(3))) void*)l, 16, 0, 0);
}

// ------------- prep: cast x, transpose-cast weights, mask tile flags -------------
__global__ __launch_bounds__(256)
void prep_k(const float* __restrict__ x,
            const float* __restrict__ Wq, const float* __restrict__ Wk,
            const float* __restrict__ Wv, const float* __restrict__ Wo,
            const int* __restrict__ mask,
            unsigned short* __restrict__ xb,
            unsigned short* __restrict__ WqT, unsigned short* __restrict__ WkT,
            unsigned short* __restrict__ WvT, unsigned short* __restrict__ WoT,
            int* __restrict__ flags)
{
  __shared__ float tile[64][68];
  __shared__ int fl[4];
  int blk = blockIdx.x;
  const int tid = threadIdx.x;
  if (blk < 4096) {                      // x cast
    size_t base = (size_t)blk * 2048 + tid * 8;
    float4 f0 = *(const float4*)&x[base];
    float4 f1 = *(const float4*)&x[base + 4];
    uint4 o;
    o.x = pk2bf(f0.x, f0.y); o.y = pk2bf(f0.z, f0.w);
    o.z = pk2bf(f1.x, f1.y); o.w = pk2bf(f1.z, f1.w);
    *(uint4*)&xb[base] = o;
    return;
  }
  blk -= 4096;
  if (blk >= 2560) {                     // mask tile flags: 512 blocks, 128x64 tiles
    int fb = blk - 2560;
    int qt = fb >> 5, tt = fb & 31;
    bool hz = false;
#pragma unroll
    for (int it = 0; it < 8; ++it) {
      int l = it * 1024 + tid * 4;
      int row = l >> 6, col = l & 63;
      int4 mv = *(const int4*)&mask[(size_t)(qt * 128 + row) * 2048 + tt * 64 + col];
      hz |= (mv.x == 0) | (mv.y == 0) | (mv.z == 0) | (mv.w == 0);
    }
    unsigned long long bal = __ballot(hz);
    if ((tid & 63) == 0) fl[tid >> 6] = (bal != 0ull) ? 1 : 0;
    __syncthreads();
    if (tid == 0) flags[fb] = fl[0] | fl[1] | fl[2] | fl[3];
    return;
  }
  const float* W; unsigned short* WT; int N;
  if (blk < 1024)      { W = Wq; WT = WqT; N = 2048; }
  else if (blk < 1280) { W = Wk; WT = WkT; N = 512;  blk -= 1024; }
  else if (blk < 1536) { W = Wv; WT = WvT; N = 512;  blk -= 1280; }
  else                 { W = Wo; WT = WoT; N = 2048; blk -= 1536; }
  const int kt = blk & 31, nt = blk >> 5;
  const int k0 = kt * 64, n0 = nt * 64;
  const int tr = tid >> 4, tc4 = (tid & 15) * 4;
#pragma unroll
  for (int it = 0; it < 4; ++it) {
    int k = it * 16 + tr;
    float4 v = *(const float4*)&W[(size_t)(k0 + k) * N + n0 + tc4];
    tile[tc4 + 0][k] = v.x; tile[tc4 + 1][k] = v.y;
    tile[tc4 + 2][k] = v.z; tile[tc4 + 3][k] = v.w;
  }
  __syncthreads();
#pragma unroll
  for (int it = 0; it < 4; ++it) {
    int n = it * 16 + tr;
    uint2 o;
    o.x = pk2bf(tile[n][tc4 + 0], tile[n][tc4 + 1]);
    o.y = pk2bf(tile[n][tc4 + 2], tile[n][tc4 + 3]);
    *(uint2*)&WT[(size_t)(n0 + n) * 2048 + k0 + tc4] = o;
  }
}

// ---------------- fused QKV GEMM: A(4096x2048) x Wqkv^T(3072x2048) ----------------
__global__ __launch_bounds__(256)
void mm_qkv(const unsigned short* __restrict__ A,
            const unsigned short* __restrict__ Wt,   // 3072 x 2048 (q|k|v rows)
            const float* __restrict__ bq, const float* __restrict__ bk,
            const float* __restrict__ bv,
            unsigned short* __restrict__ qb, unsigned short* __restrict__ kb,
            unsigned short* __restrict__ vb)
{
  __shared__ __align__(16) unsigned short As[128 * 32];
  __shared__ __align__(16) unsigned short Bs[128 * 32];
  const int tid = threadIdx.x;
  const int lane = tid & 63, w = tid >> 6;
  const int l15 = lane & 15, quad = lane >> 4;
  const int wm = w & 1, wn = w >> 1;
  const int row0 = blockIdx.y * 128;
  const int col0 = blockIdx.x * 128;

  f32x4 acc[4][4];
#pragma unroll
  for (int mt = 0; mt < 4; ++mt)
#pragma unroll
    for (int nt = 0; nt < 4; ++nt) acc[mt][nt] = (f32x4){0.f, 0.f, 0.f, 0.f};

  const int c0 = tid, c1 = 256 + tid;
  const size_t aoff0 = (size_t)(row0 + (c0 >> 2)) * 2048 + (c0 & 3) * 8;
  const size_t aoff1 = (size_t)(row0 + (c1 >> 2)) * 2048 + (c1 & 3) * 8;
  const size_t boff0 = (size_t)(col0 + (c0 >> 2)) * 2048 + (c0 & 3) * 8;
  const size_t boff1 = (size_t)(col0 + (c1 >> 2)) * 2048 + (c1 & 3) * 8;

  for (int k0 = 0; k0 < 2048; k0 += 32) {
    gl_lds16(A + aoff0 + k0, As + (size_t)c0 * 8);
    gl_lds16(A + aoff1 + k0, As + (size_t)c1 * 8);
    gl_lds16(Wt + boff0 + k0, Bs + (size_t)c0 * 8);
    gl_lds16(Wt + boff1 + k0, Bs + (size_t)c1 * 8);
    __syncthreads();
    bf16x8 af[4], bfr[4];
#pragma unroll
    for (int mt = 0; mt < 4; ++mt)
      af[mt] = *(const bf16x8*)&As[(wm * 64 + mt * 16 + l15) * 32 + quad * 8];
#pragma unroll
    for (int nt = 0; nt < 4; ++nt)
      bfr[nt] = *(const bf16x8*)&Bs[(wn * 64 + nt * 16 + l15) * 32 + quad * 8];
#pragma unroll
    for (int mt = 0; mt < 4; ++mt)
#pragma unroll
      for (int nt = 0; nt < 4; ++nt)
        acc[mt][nt] = __builtin_amdgcn_mfma_f32_16x16x32_bf16(
            af[mt], bfr[nt], acc[mt][nt], 0, 0, 0);
    __syncthreads();
  }

  const int rbase = row0 + wm * 64 + quad * 4;
#pragma unroll
  for (int nt = 0; nt < 4; ++nt) {
    const int cg = col0 + wn * 64 + nt * 16 + l15;
#pragma unroll
    for (int mt = 0; mt < 4; ++mt) {
#pragma unroll
      for (int reg = 0; reg < 4; ++reg) {
        const int r = rbase + mt * 16 + reg;
        const int bb = r >> 11, ss = r & 2047;
        float v = acc[mt][nt][reg];
        if (col0 < 2048) {               // q (block-uniform branch)
          v += bq[cg];
          int g = cg >> 8, p = (cg >> 6) & 3, d = cg & 63;
          qb[(((size_t)((bb * 8 + g) * 4 + p)) * 2048 + ss) * 64 + d] =
              f2bf(v * 0.1803368801111244f);   // 0.125 * log2(e)
        } else if (col0 < 2560) {        // k
          int cl = cg - 2048;
          v += bk[cl];
          int g = cl >> 6, d = cl & 63;
          kb[((size_t)(bb * 8 + g) * 2048 + ss) * 64 + d] = f2bf(v);
        } else {                         // v (transposed)
          int cl = cg - 2560;
          v += bv[cl];
          int g = cl >> 6, d = cl & 63;
          vb[((size_t)(bb * 8 + g) * 64 + d) * 2048 + ss] = f2bf(v);
        }
      }
    }
  }
}

// ---------------- output-projection GEMM (m97 structure, fp32 out) ----------------
__global__ __launch_bounds__(256)
void mm_out(const unsigned short* __restrict__ A,
            const unsigned short* __restrict__ Bt,
            const float* __restrict__ bias, float* __restrict__ Of)
{
  __shared__ __align__(16) unsigned short As[128 * 32];
  __shared__ __align__(16) unsigned short Bs[128 * 32];
  const int tid = threadIdx.x;
  const int lane = tid & 63, w = tid >> 6;
  const int l15 = lane & 15, quad = lane >> 4;
  const int wm = w & 1, wn = w >> 1;
  const int row0 = blockIdx.y * 128;
  const int col0 = blockIdx.x * 128;

  f32x4 acc[4][4];
#pragma unroll
  for (int mt = 0; mt < 4; ++mt)
#pragma unroll
    for (int nt = 0; nt < 4; ++nt) acc[mt][nt] = (f32x4){0.f, 0.f, 0.f, 0.f};

  const int c0 = tid, c1 = 256 + tid;
  const size_t aoff0 = (size_t)(row0 + (c0 >> 2)) * 2048 + (c0 & 3) * 8;
  const size_t aoff1 = (size_t)(row0 + (c1 >> 2)) * 2048 + (c1 & 3) * 8;
  const size_t boff0 = (size_t)(col0 + (c0 >> 2)) * 2048 + (c0 & 3) * 8;
  const size_t boff1 = (size_t)(col0 + (c1 >> 2)) * 2048 + (c1 & 3) * 8;

  for (int k0 = 0; k0 < 2048; k0 += 32) {
    gl_lds16(A + aoff0 + k0, As + (size_t)c0 * 8);
    gl_lds16(A + aoff1 + k0, As + (size_t)c1 * 8);
    gl_lds16(Bt + boff0 + k0, Bs + (size_t)c0 * 8);
    gl_lds16(Bt + boff1 + k0, Bs + (size_t)c1 * 8);
    __syncthreads();
    bf16x8 af[4], bfr[4];
#pragma unroll
    for (int mt = 0; mt < 4; ++mt)
      af[mt] = *(const bf16x8*)&As[(wm * 64 + mt * 16 + l15) * 32 + quad * 8];
#pragma unroll
    for (int nt = 0; nt < 4; ++nt)
      bfr[nt] = *(const bf16x8*)&Bs[(wn * 64 + nt * 16 + l15) * 32 + quad * 8];
#pragma unroll
    for (int mt = 0; mt < 4; ++mt)
#pragma unroll
      for (int nt = 0; nt < 4; ++nt)
        acc[mt][nt] = __builtin_amdgcn_mfma_f32_16x16x32_bf16(
            af[mt], bfr[nt], acc[mt][nt], 0, 0, 0);
    __syncthreads();
  }

  const int rbase = row0 + wm * 64 + quad * 4;
#pragma unroll
  for (int nt = 0; nt < 4; ++nt) {
    const int cg = col0 + wn * 64 + nt * 16 + l15;
    const float bvv = bias[cg];
#pragma unroll
    for (int mt = 0; mt < 4; ++mt)
#pragma unroll
      for (int reg = 0; reg < 4; ++reg) {
        const int r = rbase + mt * 16 + reg;
        Of[(size_t)r * 2048 + cg] = acc[mt][nt][reg] + bvv;
      }
  }
}

// ----- flash attention: 512 thr / 8 waves, q-tile 256, dbuf K/V, exp2 softmax -----
// Block = 256 q-rows x 1 head; 8 waves each own 32 q-rows (per-wave code
// identical to the proven round-2 form). 8 waves share one K/V staging ->
// staging instrs and kf amortization per q-row halve vs 4-wave/128-row.
// LDS = 16K(Ks)+16K(Vs)+36.9K(Ps) ~ 69KB -> 2 blocks/CU = 4 waves/SIMD
// (up from 3); VGPR <=128 via launch_bounds(512,4). Grid 8x64 = 512 blocks
// = exactly 2/CU, XCD-swizzled (512%8==0 -> bijective) so each XCD owns
// 2 whole (b,g) groups: K/V (1MB) + Q (2MB) L2-resident per XCD.
__global__ __launch_bounds__(512, 4)
void attn_k(const unsigned short* __restrict__ qb,
            const unsigned short* __restrict__ kb,
            const unsigned short* __restrict__ vb,
            const int* __restrict__ mask, const int* __restrict__ flags,
            unsigned short* __restrict__ attnb)
{
  __shared__ __align__(16) unsigned short Ks[2][64 * 64];  // [buf][t][d], swizzled
  __shared__ __align__(16) unsigned short Vs[2][64 * 64];  // [buf][d][t], swizzled
  __shared__ __align__(16) unsigned short Ps[256 * 72];    // [s_loc][t], wave-private
  const int tid = threadIdx.x;
  const int lane = tid & 63, w = tid >> 6;                 // w in [0,8)
  const int l15 = lane & 15, quad = lane >> 4;

  // XCD-aware remap (nwg=512, gridDim.x=8; x fastest in dispatch order)
  const int lid = blockIdx.y * 8 + blockIdx.x;
  const int work = (lid & 7) * 64 + (lid >> 3);
  const int qt = work & 7;              // q-tile of 256 rows
  const int pr = work >> 3;             // b(2) x g(8) x p(4)
  const int q0 = qt * 256;
  const int b = pr >> 5, g = (pr >> 2) & 7, p = pr & 3;
  const int bg = b * 8 + g;

  const unsigned short* Kg = kb + (size_t)bg * 2048 * 64;
  const unsigned short* Vg = vb + (size_t)bg * 64 * 2048;
  const unsigned short* Qg = qb + (size_t)(bg * 4 + p) * 2048 * 64;

  // Q fragments (resident)
  bf16x8 qf[2][2];                      // [u][half]
#pragma unroll
  for (int u = 0; u < 2; ++u) {
    const size_t qrow = (size_t)(q0 + w * 32 + u * 16 + l15) * 64;
    qf[u][0] = *(const bf16x8*)&Qg[qrow + quad * 8];
    qf[u][1] = *(const bf16x8*)&Qg[qrow + 32 + quad * 8];
  }

  bf16x8 ones;
#pragma unroll
  for (int i = 0; i < 8; ++i) ones[i] = (short)0x3F80;   // bf16 1.0

  f32x4 acc_o[4][2];                    // [dt][u]
  f32x4 acc_l[2];                       // [u] row-sum accumulator
#pragma unroll
  for (int u = 0; u < 2; ++u) acc_l[u] = (f32x4){0.f, 0.f, 0.f, 0.f};
#pragma unroll
  for (int dt = 0; dt < 4; ++dt)
#pragma unroll
    for (int u = 0; u < 2; ++u) acc_o[dt][u] = (f32x4){0.f, 0.f, 0.f, 0.f};

  // staging: 512 threads, one 16B chunk each per buffer
  const int kr = tid >> 3;              // [0,64)
  const int kx = ((tid & 7) ^ (kr & 7)) * 8;

  // prologue: stage tile 0 into buf 0
  gl_lds16(Kg + (size_t)kr * 64 + kx, &Ks[0][(size_t)tid * 8]);
  gl_lds16(Vg + (size_t)kr * 2048 + kx, &Vs[0][(size_t)tid * 8]);
  __syncthreads();                       // vmcnt(0) drain: tile 0 resident

  for (int it = 0; it < 32; ++it) {
    const int cur = it & 1;
    const int t0 = it << 6;
    if (it < 31) {                       // issue next tile's staging FIRST
      const int tn = t0 + 64;
      gl_lds16(Kg + (size_t)(tn + kr) * 64 + kx, &Ks[cur ^ 1][(size_t)tid * 8]);
      gl_lds16(Vg + (size_t)kr * 2048 + tn + kx, &Vs[cur ^ 1][(size_t)tid * 8]);
    }
    const unsigned short* Kc = Ks[cur];
    const unsigned short* Vc = Vs[cur];

    // K fragments
    bf16x8 kf[4][2];
#pragma unroll
    for (int nt = 0; nt < 4; ++nt) {
      const int trow = nt * 16 + l15, ks = trow & 7;
      kf[nt][0] = *(const bf16x8*)&Kc[trow * 64 + ((quad ^ ks) * 8)];
      kf[nt][1] = *(const bf16x8*)&Kc[trow * 64 + (((4 + quad) ^ ks) * 8)];
    }
    const bool msk = flags[(qt * 2 + (w >> 2)) * 32 + it] != 0;

    // S^T = K Q^T -> exp2 -> P^T into Ps (per u-subtile)
#pragma unroll
    for (int u = 0; u < 2; ++u) {
      f32x4 st[4];
#pragma unroll
      for (int nt = 0; nt < 4; ++nt) {
        f32x4 z = (f32x4){0.f, 0.f, 0.f, 0.f};
        z = __builtin_amdgcn_mfma_f32_16x16x32_bf16(kf[nt][0], qf[u][0], z, 0, 0, 0);
        st[nt] = __builtin_amdgcn_mfma_f32_16x16x32_bf16(kf[nt][1], qf[u][1], z, 0, 0, 0);
      }
      if (msk) {
        const size_t mrow = (size_t)(q0 + w * 32 + u * 16 + l15) * 2048;
#pragma unroll
        for (int nt = 0; nt < 4; ++nt) {
          int4 mv = *(const int4*)&mask[mrow + t0 + nt * 16 + quad * 4];
          if (mv.x == 0) st[nt][0] = -1e30f;
          if (mv.y == 0) st[nt][1] = -1e30f;
          if (mv.z == 0) st[nt][2] = -1e30f;
          if (mv.w == 0) st[nt][3] = -1e30f;
        }
      }
      const int srow = w * 32 + u * 16 + l15;
#pragma unroll
      for (int nt = 0; nt < 4; ++nt) {
        float p0 = __builtin_amdgcn_exp2f(st[nt][0]);
        float p1 = __builtin_amdgcn_exp2f(st[nt][1]);
        float p2 = __builtin_amdgcn_exp2f(st[nt][2]);
        float p3 = __builtin_amdgcn_exp2f(st[nt][3]);
        uint2 pkd;
        pkd.x = pk2bf(p0, p1);
        pkd.y = pk2bf(p2, p3);
        *(uint2*)&Ps[srow * 72 + nt * 16 + quad * 4] = pkd;
      }
    }
    asm volatile("s_waitcnt lgkmcnt(0)" ::: "memory");  // Ps rows wave-private

    bf16x8 pf[2][2];
#pragma unroll
    for (int u = 0; u < 2; ++u) {
      const int srow = w * 32 + u * 16 + l15;
      pf[u][0] = *(const bf16x8*)&Ps[srow * 72 + quad * 8];
      pf[u][1] = *(const bf16x8*)&Ps[srow * 72 + 32 + quad * 8];
      // l += 1-vector . P^T  (every lane gets the full 32-key sum)
      acc_l[u] = __builtin_amdgcn_mfma_f32_16x16x32_bf16(ones, pf[u][0], acc_l[u], 0, 0, 0);
      acc_l[u] = __builtin_amdgcn_mfma_f32_16x16x32_bf16(ones, pf[u][1], acc_l[u], 0, 0, 0);
    }
    // O^T += V^T P^T
#pragma unroll
    for (int dt = 0; dt < 4; ++dt) {
      const int drow = dt * 16 + l15, ks = drow & 7;
      bf16x8 v0 = *(const bf16x8*)&Vc[drow * 64 + ((quad ^ ks) * 8)];
      bf16x8 v1 = *(const bf16x8*)&Vc[drow * 64 + (((4 + quad) ^ ks) * 8)];
#pragma unroll
      for (int u = 0; u < 2; ++u) {
        acc_o[dt][u] = __builtin_amdgcn_mfma_f32_16x16x32_bf16(v0, pf[u][0], acc_o[dt][u], 0, 0, 0);
        acc_o[dt][u] = __builtin_amdgcn_mfma_f32_16x16x32_bf16(v1, pf[u][1], acc_o[dt][u], 0, 0, 0);
      }
    }
    __syncthreads();   // reads(t) done; next-tile staging (vmcnt) drained here
  }

  // epilogue: O^T / l  (l identical across quads and regs -> no reduction)
  const int hh = g * 4 + p;
#pragma unroll
  for (int u = 0; u < 2; ++u) {
    const float inv = 1.0f / acc_l[u][0];
    const int s = q0 + w * 32 + u * 16 + l15;
#pragma unroll
    for (int dt = 0; dt < 4; ++dt) {
      uint2 o;
      o.x = pk2bf(acc_o[dt][u][0] * inv, acc_o[dt][u][1] * inv);
      o.y = pk2bf(acc_o[dt][u][2] * inv, acc_o[dt][u][3] * inv);
      *(uint2*)&attnb[((size_t)(b * 2048 + s)) * 2048 + hh * 64 + dt * 16 + quad * 4] = o;
    }
  }
}

extern "C" void kernel_launch(void* const* d_in, const int* in_sizes, int n_in,
                              void* d_out, int out_size, void* d_ws, size_t ws_size,
                              hipStream_t stream)
{
  (void)in_sizes; (void)n_in; (void)out_size; (void)ws_size;
  const float* x  = (const float*)d_in[0];
  const int* mask = (const int*)d_in[1];
  const float* Wq = (const float*)d_in[2];
  const float* bq = (const float*)d_in[3];
  const float* Wk = (const float*)d_in[4];
  const float* bk = (const float*)d_in[5];
  const float* Wv = (const float*)d_in[6];
  const float* bv = (const float*)d_in[7];
  const float* Wo = (const float*)d_in[8];
  const float* bo = (const float*)d_in[9];
  float* out = (float*)d_out;

  unsigned short* xb  = (unsigned short*)d_ws;       // 8388608
  unsigned short* WqT = xb  + 8388608;               // 4194304 (qkv contiguous)
  unsigned short* WkT = WqT + 4194304;               // 1048576 (qkv contiguous)
  unsigned short* WvT = WkT + 1048576;               // 1048576 (qkv contiguous)
  unsigned short* WoT = WvT + 1048576;               // 4194304
  unsigned short* qb  = WoT + 4194304;               // 8388608
  unsigned short* kb  = qb  + 8388608;               // 2097152
  unsigned short* vb  = kb  + 2097152;               // 2097152
  int* flags = (int*)(vb + 2097152);                 // 512 ints
  unsigned short* attnb = xb;                        // reuse

  hipLaunchKernelGGL(prep_k, dim3(7168), dim3(256), 0, stream,
                     x, Wq, Wk, Wv, Wo, mask, xb, WqT, WkT, WvT, WoT, flags);
  hipLaunchKernelGGL(mm_qkv, dim3(24, 32), dim3(256), 0, stream,
                     xb, WqT, bq, bk, bv, qb, kb, vb);
  hipLaunchKernelGGL(attn_k, dim3(8, 64), dim3(512), 0, stream,
                     qb, kb, vb, mask, flags, attnb);
  hipLaunchKernelGGL(mm_out, dim3(16, 32), dim3(256), 0, stream,
                     attnb, WoT, bo, out);
}

// Round 6
// 335.595 us; speedup vs baseline: 1.2243x; 1.0406x over previous
//
#include <hip/hip_runtime.h>
#include <hip/hip_bf16.h>

// GQA bf16-MFMA pipeline. B=2, S=2048, H=2048, 32 heads = 8 groups x 4, d=64.
// prep_k:   x -> xb (bf16); W* -> W*T (N x K bf16, contiguous qkv+o); mask flags
// mm_qkv:   one GEMM over N=3072 (m97 128^2 structure + XCD-swizzled block
//           order, 768%8==0 bijective): qb(scaled,scatter) | kb | vb(transposed)
// attn_k:   flash S^T/O^T, 512 thr / 8 waves, q-tile 256, 1 head/block,
//           double-buffered K/V (2-phase), XCD-swizzled, s_setprio around
//           MFMA clusters (T5: +4-7% attn, m191), no-max exp2 softmax,
//           row-sum l via all-ones MFMA.
// mm_out:   out = attnb Wo + bo (fp32), m97 structure + XCD swizzle (512%8==0).
// attnb reuses xb (dead after projections). WqT..WvT contiguous = 3072x2048.

#define DEVINL __device__ __forceinline__

typedef __attribute__((ext_vector_type(8))) short bf16x8;
typedef __attribute__((ext_vector_type(4))) float f32x4;

DEVINL unsigned short f2bf(float f) {
  unsigned u = __builtin_bit_cast(unsigned, f);
  u += 0x7fffu + ((u >> 16) & 1u);          // RNE
  return (unsigned short)(u >> 16);
}

DEVINL unsigned pk2bf(float a, float b) {   // HW v_cvt_pk_bf16_f32 (RNE)
  __hip_bfloat162 h = __float22bfloat162_rn(float2{a, b});
  unsigned r;
  __builtin_memcpy(&r, &h, 4);
  return r;
}

DEVINL void gl_lds16(const void* g, void* l) {
  __builtin_amdgcn_global_load_lds(
      (const __attribute__((address_space(1))) void*)g,
      (__attribute__((address_space(3))) void*)l, 16, 0, 0);
}

// ------------- prep: cast x, transpose-cast weights, mask tile flags -------------
__global__ __launch_bounds__(256)
void prep_k(const float* __restrict__ x,
            const float* __restrict__ Wq, const float* __restrict__ Wk,
            const float* __restrict__ Wv, const float* __restrict__ Wo,
            const int* __restrict__ mask,
            unsigned short* __restrict__ xb,
            unsigned short* __restrict__ WqT, unsigned short* __restrict__ WkT,
            unsigned short* __restrict__ WvT, unsigned short* __restrict__ WoT,
            int* __restrict__ flags)
{
  __shared__ float tile[64][68];
  __shared__ int fl[4];
  int blk = blockIdx.x;
  const int tid = threadIdx.x;
  if (blk < 4096) {                      // x cast
    size_t base = (size_t)blk * 2048 + tid * 8;
    float4 f0 = *(const float4*)&x[base];
    float4 f1 = *(const float4*)&x[base + 4];
    uint4 o;
    o.x = pk2bf(f0.x, f0.y); o.y = pk2bf(f0.z, f0.w);
    o.z = pk2bf(f1.x, f1.y); o.w = pk2bf(f1.z, f1.w);
    *(uint4*)&xb[base] = o;
    return;
  }
  blk -= 4096;
  if (blk >= 2560) {                     // mask tile flags: 512 blocks, 128x64 tiles
    int fb = blk - 2560;
    int qt = fb >> 5, tt = fb & 31;
    bool hz = false;
#pragma unroll
    for (int it = 0; it < 8; ++it) {
      int l = it * 1024 + tid * 4;
      int row = l >> 6, col = l & 63;
      int4 mv = *(const int4*)&mask[(size_t)(qt * 128 + row) * 2048 + tt * 64 + col];
      hz |= (mv.x == 0) | (mv.y == 0) | (mv.z == 0) | (mv.w == 0);
    }
    unsigned long long bal = __ballot(hz);
    if ((tid & 63) == 0) fl[tid >> 6] = (bal != 0ull) ? 1 : 0;
    __syncthreads();
    if (tid == 0) flags[fb] = fl[0] | fl[1] | fl[2] | fl[3];
    return;
  }
  const float* W; unsigned short* WT; int N;
  if (blk < 1024)      { W = Wq; WT = WqT; N = 2048; }
  else if (blk < 1280) { W = Wk; WT = WkT; N = 512;  blk -= 1024; }
  else if (blk < 1536) { W = Wv; WT = WvT; N = 512;  blk -= 1280; }
  else                 { W = Wo; WT = WoT; N = 2048; blk -= 1536; }
  const int kt = blk & 31, nt = blk >> 5;
  const int k0 = kt * 64, n0 = nt * 64;
  const int tr = tid >> 4, tc4 = (tid & 15) * 4;
#pragma unroll
  for (int it = 0; it < 4; ++it) {
    int k = it * 16 + tr;
    float4 v = *(const float4*)&W[(size_t)(k0 + k) * N + n0 + tc4];
    tile[tc4 + 0][k] = v.x; tile[tc4 + 1][k] = v.y;
    tile[tc4 + 2][k] = v.z; tile[tc4 + 3][k] = v.w;
  }
  __syncthreads();
#pragma unroll
  for (int it = 0; it < 4; ++it) {
    int n = it * 16 + tr;
    uint2 o;
    o.x = pk2bf(tile[n][tc4 + 0], tile[n][tc4 + 1]);
    o.y = pk2bf(tile[n][tc4 + 2], tile[n][tc4 + 3]);
    *(uint2*)&WT[(size_t)(n0 + n) * 2048 + k0 + tc4] = o;
  }
}

// ---------------- fused QKV GEMM: A(4096x2048) x Wqkv^T(3072x2048) ----------------
__global__ __launch_bounds__(256)
void mm_qkv(const unsigned short* __restrict__ A,
            const unsigned short* __restrict__ Wt,   // 3072 x 2048 (q|k|v rows)
            const float* __restrict__ bq, const float* __restrict__ bk,
            const float* __restrict__ bv,
            unsigned short* __restrict__ qb, unsigned short* __restrict__ kb,
            unsigned short* __restrict__ vb)
{
  __shared__ __align__(16) unsigned short As[128 * 32];
  __shared__ __align__(16) unsigned short Bs[128 * 32];
  const int tid = threadIdx.x;
  const int lane = tid & 63, w = tid >> 6;
  const int l15 = lane & 15, quad = lane >> 4;
  const int wm = w & 1, wn = w >> 1;
  // XCD swizzle: grid 24x32 = 768 blocks, 768%8==0 -> bijective. Each XCD gets
  // 96 contiguous (row-major) blocks = 4 whole A row-panels (2MB, L2-resident).
  const int wg = blockIdx.y * 24 + blockIdx.x;
  const int swz = (wg & 7) * 96 + (wg >> 3);
  const int row0 = (swz / 24) * 128;
  const int col0 = (swz % 24) * 128;

  f32x4 acc[4][4];
#pragma unroll
  for (int mt = 0; mt < 4; ++mt)
#pragma unroll
    for (int nt = 0; nt < 4; ++nt) acc[mt][nt] = (f32x4){0.f, 0.f, 0.f, 0.f};

  const int c0 = tid, c1 = 256 + tid;
  const size_t aoff0 = (size_t)(row0 + (c0 >> 2)) * 2048 + (c0 & 3) * 8;
  const size_t aoff1 = (size_t)(row0 + (c1 >> 2)) * 2048 + (c1 & 3) * 8;
  const size_t boff0 = (size_t)(col0 + (c0 >> 2)) * 2048 + (c0 & 3) * 8;
  const size_t boff1 = (size_t)(col0 + (c1 >> 2)) * 2048 + (c1 & 3) * 8;

  for (int k0 = 0; k0 < 2048; k0 += 32) {
    gl_lds16(A + aoff0 + k0, As + (size_t)c0 * 8);
    gl_lds16(A + aoff1 + k0, As + (size_t)c1 * 8);
    gl_lds16(Wt + boff0 + k0, Bs + (size_t)c0 * 8);
    gl_lds16(Wt + boff1 + k0, Bs + (size_t)c1 * 8);
    __syncthreads();
    bf16x8 af[4], bfr[4];
#pragma unroll
    for (int mt = 0; mt < 4; ++mt)
      af[mt] = *(const bf16x8*)&As[(wm * 64 + mt * 16 + l15) * 32 + quad * 8];
#pragma unroll
    for (int nt = 0; nt < 4; ++nt)
      bfr[nt] = *(const bf16x8*)&Bs[(wn * 64 + nt * 16 + l15) * 32 + quad * 8];
#pragma unroll
    for (int mt = 0; mt < 4; ++mt)
#pragma unroll
      for (int nt = 0; nt < 4; ++nt)
        acc[mt][nt] = __builtin_amdgcn_mfma_f32_16x16x32_bf16(
            af[mt], bfr[nt], acc[mt][nt], 0, 0, 0);
    __syncthreads();
  }

  const int rbase = row0 + wm * 64 + quad * 4;
#pragma unroll
  for (int nt = 0; nt < 4; ++nt) {
    const int cg = col0 + wn * 64 + nt * 16 + l15;
#pragma unroll
    for (int mt = 0; mt < 4; ++mt) {
#pragma unroll
      for (int reg = 0; reg < 4; ++reg) {
        const int r = rbase + mt * 16 + reg;
        const int bb = r >> 11, ss = r & 2047;
        float v = acc[mt][nt][reg];
        if (col0 < 2048) {               // q (block-uniform branch)
          v += bq[cg];
          int g = cg >> 8, p = (cg >> 6) & 3, d = cg & 63;
          qb[(((size_t)((bb * 8 + g) * 4 + p)) * 2048 + ss) * 64 + d] =
              f2bf(v * 0.1803368801111244f);   // 0.125 * log2(e)
        } else if (col0 < 2560) {        // k
          int cl = cg - 2048;
          v += bk[cl];
          int g = cl >> 6, d = cl & 63;
          kb[((size_t)(bb * 8 + g) * 2048 + ss) * 64 + d] = f2bf(v);
        } else {                         // v (transposed)
          int cl = cg - 2560;
          v += bv[cl];
          int g = cl >> 6, d = cl & 63;
          vb[((size_t)(bb * 8 + g) * 64 + d) * 2048 + ss] = f2bf(v);
        }
      }
    }
  }
}

// ---------------- output-projection GEMM (m97 structure, fp32 out) ----------------
__global__ __launch_bounds__(256)
void mm_out(const unsigned short* __restrict__ A,
            const unsigned short* __restrict__ Bt,
            const float* __restrict__ bias, float* __restrict__ Of)
{
  __shared__ __align__(16) unsigned short As[128 * 32];
  __shared__ __align__(16) unsigned short Bs[128 * 32];
  const int tid = threadIdx.x;
  const int lane = tid & 63, w = tid >> 6;
  const int l15 = lane & 15, quad = lane >> 4;
  const int wm = w & 1, wn = w >> 1;
  // XCD swizzle: grid 16x32 = 512 blocks, 512%8==0 -> bijective.
  const int wg = blockIdx.y * 16 + blockIdx.x;
  const int swz = (wg & 7) * 64 + (wg >> 3);
  const int row0 = (swz >> 4) * 128;
  const int col0 = (swz & 15) * 128;

  f32x4 acc[4][4];
#pragma unroll
  for (int mt = 0; mt < 4; ++mt)
#pragma unroll
    for (int nt = 0; nt < 4; ++nt) acc[mt][nt] = (f32x4){0.f, 0.f, 0.f, 0.f};

  const int c0 = tid, c1 = 256 + tid;
  const size_t aoff0 = (size_t)(row0 + (c0 >> 2)) * 2048 + (c0 & 3) * 8;
  const size_t aoff1 = (size_t)(row0 + (c1 >> 2)) * 2048 + (c1 & 3) * 8;
  const size_t boff0 = (size_t)(col0 + (c0 >> 2)) * 2048 + (c0 & 3) * 8;
  const size_t boff1 = (size_t)(col0 + (c1 >> 2)) * 2048 + (c1 & 3) * 8;

  for (int k0 = 0; k0 < 2048; k0 += 32) {
    gl_lds16(A + aoff0 + k0, As + (size_t)c0 * 8);
    gl_lds16(A + aoff1 + k0, As + (size_t)c1 * 8);
    gl_lds16(Bt + boff0 + k0, Bs + (size_t)c0 * 8);
    gl_lds16(Bt + boff1 + k0, Bs + (size_t)c1 * 8);
    __syncthreads();
    bf16x8 af[4], bfr[4];
#pragma unroll
    for (int mt = 0; mt < 4; ++mt)
      af[mt] = *(const bf16x8*)&As[(wm * 64 + mt * 16 + l15) * 32 + quad * 8];
#pragma unroll
    for (int nt = 0; nt < 4; ++nt)
      bfr[nt] = *(const bf16x8*)&Bs[(wn * 64 + nt * 16 + l15) * 32 + quad * 8];
#pragma unroll
    for (int mt = 0; mt < 4; ++mt)
#pragma unroll
      for (int nt = 0; nt < 4; ++nt)
        acc[mt][nt] = __builtin_amdgcn_mfma_f32_16x16x32_bf16(
            af[mt], bfr[nt], acc[mt][nt], 0, 0, 0);
    __syncthreads();
  }

  const int rbase = row0 + wm * 64 + quad * 4;
#pragma unroll
  for (int nt = 0; nt < 4; ++nt) {
    const int cg = col0 + wn * 64 + nt * 16 + l15;
    const float bvv = bias[cg];
#pragma unroll
    for (int mt = 0; mt < 4; ++mt)
#pragma unroll
      for (int reg = 0; reg < 4; ++reg) {
        const int r = rbase + mt * 16 + reg;
        Of[(size_t)r * 2048 + cg] = acc[mt][nt][reg] + bvv;
      }
  }
}

// ----- flash attention: 512 thr / 8 waves, q-tile 256, dbuf K/V, exp2 softmax -----
// (round-5 structure + T5 setprio around MFMA clusters)
__global__ __launch_bounds__(512, 4)
void attn_k(const unsigned short* __restrict__ qb,
            const unsigned short* __restrict__ kb,
            const unsigned short* __restrict__ vb,
            const int* __restrict__ mask, const int* __restrict__ flags,
            unsigned short* __restrict__ attnb)
{
  __shared__ __align__(16) unsigned short Ks[2][64 * 64];  // [buf][t][d], swizzled
  __shared__ __align__(16) unsigned short Vs[2][64 * 64];  // [buf][d][t], swizzled
  __shared__ __align__(16) unsigned short Ps[256 * 72];    // [s_loc][t], wave-private
  const int tid = threadIdx.x;
  const int lane = tid & 63, w = tid >> 6;                 // w in [0,8)
  const int l15 = lane & 15, quad = lane >> 4;

  // XCD-aware remap (nwg=512, gridDim.x=8; x fastest in dispatch order)
  const int lid = blockIdx.y * 8 + blockIdx.x;
  const int work = (lid & 7) * 64 + (lid >> 3);
  const int qt = work & 7;              // q-tile of 256 rows
  const int pr = work >> 3;             // b(2) x g(8) x p(4)
  const int q0 = qt * 256;
  const int b = pr >> 5, g = (pr >> 2) & 7, p = pr & 3;
  const int bg = b * 8 + g;

  const unsigned short* Kg = kb + (size_t)bg * 2048 * 64;
  const unsigned short* Vg = vb + (size_t)bg * 64 * 2048;
  const unsigned short* Qg = qb + (size_t)(bg * 4 + p) * 2048 * 64;

  // Q fragments (resident)
  bf16x8 qf[2][2];                      // [u][half]
#pragma unroll
  for (int u = 0; u < 2; ++u) {
    const size_t qrow = (size_t)(q0 + w * 32 + u * 16 + l15) * 64;
    qf[u][0] = *(const bf16x8*)&Qg[qrow + quad * 8];
    qf[u][1] = *(const bf16x8*)&Qg[qrow + 32 + quad * 8];
  }

  bf16x8 ones;
#pragma unroll
  for (int i = 0; i < 8; ++i) ones[i] = (short)0x3F80;   // bf16 1.0

  f32x4 acc_o[4][2];                    // [dt][u]
  f32x4 acc_l[2];                       // [u] row-sum accumulator
#pragma unroll
  for (int u = 0; u < 2; ++u) acc_l[u] = (f32x4){0.f, 0.f, 0.f, 0.f};
#pragma unroll
  for (int dt = 0; dt < 4; ++dt)
#pragma unroll
    for (int u = 0; u < 2; ++u) acc_o[dt][u] = (f32x4){0.f, 0.f, 0.f, 0.f};

  // staging: 512 threads, one 16B chunk each per buffer
  const int kr = tid >> 3;              // [0,64)
  const int kx = ((tid & 7) ^ (kr & 7)) * 8;

  // prologue: stage tile 0 into buf 0
  gl_lds16(Kg + (size_t)kr * 64 + kx, &Ks[0][(size_t)tid * 8]);
  gl_lds16(Vg + (size_t)kr * 2048 + kx, &Vs[0][(size_t)tid * 8]);
  __syncthreads();                       // vmcnt(0) drain: tile 0 resident

  for (int it = 0; it < 32; ++it) {
    const int cur = it & 1;
    const int t0 = it << 6;
    if (it < 31) {                       // issue next tile's staging FIRST
      const int tn = t0 + 64;
      gl_lds16(Kg + (size_t)(tn + kr) * 64 + kx, &Ks[cur ^ 1][(size_t)tid * 8]);
      gl_lds16(Vg + (size_t)kr * 2048 + tn + kx, &Vs[cur ^ 1][(size_t)tid * 8]);
    }
    const unsigned short* Kc = Ks[cur];
    const unsigned short* Vc = Vs[cur];

    // K fragments
    bf16x8 kf[4][2];
#pragma unroll
    for (int nt = 0; nt < 4; ++nt) {
      const int trow = nt * 16 + l15, ks = trow & 7;
      kf[nt][0] = *(const bf16x8*)&Kc[trow * 64 + ((quad ^ ks) * 8)];
      kf[nt][1] = *(const bf16x8*)&Kc[trow * 64 + (((4 + quad) ^ ks) * 8)];
    }
    const bool msk = flags[(qt * 2 + (w >> 2)) * 32 + it] != 0;

    // S^T = K Q^T -> exp2 -> P^T into Ps (per u-subtile)
#pragma unroll
    for (int u = 0; u < 2; ++u) {
      f32x4 st[4];
      __builtin_amdgcn_s_setprio(1);
#pragma unroll
      for (int nt = 0; nt < 4; ++nt) {
        f32x4 z = (f32x4){0.f, 0.f, 0.f, 0.f};
        z = __builtin_amdgcn_mfma_f32_16x16x32_bf16(kf[nt][0], qf[u][0], z, 0, 0, 0);
        st[nt] = __builtin_amdgcn_mfma_f32_16x16x32_bf16(kf[nt][1], qf[u][1], z, 0, 0, 0);
      }
      __builtin_amdgcn_s_setprio(0);
      if (msk) {
        const size_t mrow = (size_t)(q0 + w * 32 + u * 16 + l15) * 2048;
#pragma unroll
        for (int nt = 0; nt < 4; ++nt) {
          int4 mv = *(const int4*)&mask[mrow + t0 + nt * 16 + quad * 4];
          if (mv.x == 0) st[nt][0] = -1e30f;
          if (mv.y == 0) st[nt][1] = -1e30f;
          if (mv.z == 0) st[nt][2] = -1e30f;
          if (mv.w == 0) st[nt][3] = -1e30f;
        }
      }
      const int srow = w * 32 + u * 16 + l15;
#pragma unroll
      for (int nt = 0; nt < 4; ++nt) {
        float p0 = __builtin_amdgcn_exp2f(st[nt][0]);
        float p1 = __builtin_amdgcn_exp2f(st[nt][1]);
        float p2 = __builtin_amdgcn_exp2f(st[nt][2]);
        float p3 = __builtin_amdgcn_exp2f(st[nt][3]);
        uint2 pkd;
        pkd.x = pk2bf(p0, p1);
        pkd.y = pk2bf(p2, p3);
        *(uint2*)&Ps[srow * 72 + nt * 16 + quad * 4] = pkd;
      }
    }
    asm volatile("s_waitcnt lgkmcnt(0)" ::: "memory");  // Ps rows wave-private

    bf16x8 pf[2][2];
    __builtin_amdgcn_s_setprio(1);
#pragma unroll
    for (int u = 0; u < 2; ++u) {
      const int srow = w * 32 + u * 16 + l15;
      pf[u][0] = *(const bf16x8*)&Ps[srow * 72 + quad * 8];
      pf[u][1] = *(const bf16x8*)&Ps[srow * 72 + 32 + quad * 8];
      // l += 1-vector . P^T  (every lane gets the full 32-key sum)
      acc_l[u] = __builtin_amdgcn_mfma_f32_16x16x32_bf16(ones, pf[u][0], acc_l[u], 0, 0, 0);
      acc_l[u] = __builtin_amdgcn_mfma_f32_16x16x32_bf16(ones, pf[u][1], acc_l[u], 0, 0, 0);
    }
    // O^T += V^T P^T
#pragma unroll
    for (int dt = 0; dt < 4; ++dt) {
      const int drow = dt * 16 + l15, ks = drow & 7;
      bf16x8 v0 = *(const bf16x8*)&Vc[drow * 64 + ((quad ^ ks) * 8)];
      bf16x8 v1 = *(const bf16x8*)&Vc[drow * 64 + (((4 + quad) ^ ks) * 8)];
#pragma unroll
      for (int u = 0; u < 2; ++u) {
        acc_o[dt][u] = __builtin_amdgcn_mfma_f32_16x16x32_bf16(v0, pf[u][0], acc_o[dt][u], 0, 0, 0);
        acc_o[dt][u] = __builtin_amdgcn_mfma_f32_16x16x32_bf16(v1, pf[u][1], acc_o[dt][u], 0, 0, 0);
      }
    }
    __builtin_amdgcn_s_setprio(0);
    __syncthreads();   // reads(t) done; next-tile staging (vmcnt) drained here
  }

  // epilogue: O^T / l  (l identical across quads and regs -> no reduction)
  const int hh = g * 4 + p;
#pragma unroll
  for (int u = 0; u < 2; ++u) {
    const float inv = 1.0f / acc_l[u][0];
    const int s = q0 + w * 32 + u * 16 + l15;
#pragma unroll
    for (int dt = 0; dt < 4; ++dt) {
      uint2 o;
      o.x = pk2bf(acc_o[dt][u][0] * inv, acc_o[dt][u][1] * inv);
      o.y = pk2bf(acc_o[dt][u][2] * inv, acc_o[dt][u][3] * inv);
      *(uint2*)&attnb[((size_t)(b * 2048 + s)) * 2048 + hh * 64 + dt * 16 + quad * 4] = o;
    }
  }
}

extern "C" void kernel_launch(void* const* d_in, const int* in_sizes, int n_in,
                              void* d_out, int out_size, void* d_ws, size_t ws_size,
                              hipStream_t stream)
{
  (void)in_sizes; (void)n_in; (void)out_size; (void)ws_size;
  const float* x  = (const float*)d_in[0];
  const int* mask = (const int*)d_in[1];
  const float* Wq = (const float*)d_in[2];
  const float* bq = (const float*)d_in[3];
  const float* Wk = (const float*)d_in[4];
  const float* bk = (const float*)d_in[5];
  const float* Wv = (const float*)d_in[6];
  const float* bv = (const float*)d_in[7];
  const float* Wo = (const float*)d_in[8];
  const float* bo = (const float*)d_in[9];
  float* out = (float*)d_out;

  unsigned short* xb  = (unsigned short*)d_ws;       // 8388608
  unsigned short* WqT = xb  + 8388608;               // 4194304 (qkv contiguous)
  unsigned short* WkT = WqT + 4194304;               // 1048576 (qkv contiguous)
  unsigned short* WvT = WkT + 1048576;               // 1048576 (qkv contiguous)
  unsigned short* WoT = WvT + 1048576;               // 4194304
  unsigned short* qb  = WoT + 4194304;               // 8388608
  unsigned short* kb  = qb  + 8388608;               // 2097152
  unsigned short* vb  = kb  + 2097152;               // 2097152
  int* flags = (int*)(vb + 2097152);                 // 512 ints
  unsigned short* attnb = xb;                        // reuse

  hipLaunchKernelGGL(prep_k, dim3(7168), dim3(256), 0, stream,
                     x, Wq, Wk, Wv, Wo, mask, xb, WqT, WkT, WvT, WoT, flags);
  hipLaunchKernelGGL(mm_qkv, dim3(24, 32), dim3(256), 0, stream,
                     xb, WqT, bq, bk, bv, qb, kb, vb);
  hipLaunchKernelGGL(attn_k, dim3(8, 64), dim3(512), 0, stream,
                     qb, kb, vb, mask, flags, attnb);
  hipLaunchKernelGGL(mm_out, dim3(16, 32), dim3(256), 0, stream,
                     attnb, WoT, bo, out);
}